// Round 15
// baseline (571.630 us; speedup 1.0000x reference)
//
#include <hip/hip_runtime.h>

typedef unsigned short u16;
typedef short s16x8 __attribute__((ext_vector_type(8)));
typedef float f32x4 __attribute__((ext_vector_type(4)));
typedef const __attribute__((address_space(1))) unsigned int* as1_u32p;
typedef __attribute__((address_space(3))) unsigned int* as3_u32p;

static_assert(sizeof(s16x8) == 16, "");

struct alignas(8) U16x4 { u16 x, y, z, w; };

__device__ __forceinline__ u16 f2bf(float f) {
  union { float f; unsigned u; } c; c.f = f;
  return (u16)((c.u + 0x7fffu + ((c.u >> 16) & 1u)) >> 16);
}
__device__ __forceinline__ float bf2f(u16 h) {
  union { unsigned u; float f; } c; c.u = ((unsigned)h) << 16;
  return c.f;
}
__device__ __forceinline__ void async16(const void* g, void* l) {
  __builtin_amdgcn_global_load_lds((as1_u32p)g, (as3_u32p)l, 16, 0, 0);
}

// ---------------- MEGA prep ----------------
// [0,3456): XL transpose {Waq,Wak,Wav}->WTbE(3072), {Wq,Wk,Wv}->WTbM(3136):
//   128(k) x 128(n) per block = 4x4 32x33-padded micro-tiles; source rows read
//   as 512B contiguous spans (4 lines issued together), dest rows 256B spans.
// [3456,4480): lora_dn3 -> tl
// [4480,7553): Wod[k][16] = Wo[k,:]@lp_dn (row 3072 = bo@lp_dn)
// [7553,13929): hs convert (tail zeroed), ehs, img, bias packs, WTbM QKV K-tails
__launch_bounds__(256)
__global__ void mega_prep(const float* __restrict__ Waq, const float* __restrict__ Wak,
                          const float* __restrict__ Wav, const float* __restrict__ Wq,
                          const float* __restrict__ Wk, const float* __restrict__ Wv,
                          u16* __restrict__ WTbE, u16* __restrict__ WTbM,
                          const float* __restrict__ Wo, const float* __restrict__ bo,
                          const float* __restrict__ lp_dn, float* __restrict__ Wod,
                          const float* __restrict__ d0, const float* __restrict__ d1,
                          const float* __restrict__ d2, float* __restrict__ tl,
                          const float* __restrict__ hs, u16* __restrict__ hsb,
                          const float* __restrict__ ehs, u16* __restrict__ ehsb,
                          const float* __restrict__ img, u16* __restrict__ imgb,
                          const float* __restrict__ baq, const float* __restrict__ bak,
                          const float* __restrict__ bav, const float* __restrict__ bq,
                          const float* __restrict__ bk, const float* __restrict__ bv,
                          float* __restrict__ bpk,
                          const float* __restrict__ u0, const float* __restrict__ u1,
                          const float* __restrict__ u2) {
  __shared__ char lmem[67584];
  const int b = blockIdx.x;
  const int tid = threadIdx.x;
  if (b < 3456) {  // XL transpose: 128k x 128n
    int mat = b / 576, tile = b % 576;
    const float* src = (mat == 0) ? Waq : (mat == 1) ? Wak : (mat == 2) ? Wav
                       : (mat == 3) ? Wq : (mat == 4) ? Wk : Wv;
    u16* dst = (mat < 3) ? WTbE + (long)mat * 3072 * 3072
                         : WTbM + (long)(mat - 3) * 3072 * 3136;
    const int ldd = (mat < 3) ? 3072 : 3136;
    float (*t2)[4][32][33] = (float(*)[4][32][33])lmem;
    int k0 = (tile / 24) * 128, n0 = (tile % 24) * 128;
    int r = tid >> 3, c4 = (tid & 7) * 4;
    float4 v[4][4];
#pragma unroll
    for (int i = 0; i < 4; ++i)
#pragma unroll
      for (int j = 0; j < 4; ++j)
        v[i][j] = *(const float4*)(src + (long)(k0 + i * 32 + r) * 3072 + n0 + j * 32 + c4);
#pragma unroll
    for (int i = 0; i < 4; ++i)
#pragma unroll
      for (int j = 0; j < 4; ++j) {
        t2[i][j][r][c4 + 0] = v[i][j].x; t2[i][j][r][c4 + 1] = v[i][j].y;
        t2[i][j][r][c4 + 2] = v[i][j].z; t2[i][j][r][c4 + 3] = v[i][j].w;
      }
    __syncthreads();
#pragma unroll
    for (int j = 0; j < 4; ++j)
#pragma unroll
      for (int i = 0; i < 4; ++i) {
        U16x4 o{f2bf(t2[i][j][c4 + 0][r]), f2bf(t2[i][j][c4 + 1][r]),
                f2bf(t2[i][j][c4 + 2][r]), f2bf(t2[i][j][c4 + 3][r])};
        *(U16x4*)(dst + (long)(n0 + j * 32 + r) * ldd + k0 + i * 32 + c4) = o;
      }
  } else if (b < 4480) {  // lora_dn3
    const int m = b - 3456;
    float (*red)[48] = (float(*)[48])lmem;
    const float* xr = hs + (long)(1024 + m) * 3072;
    float p[48];
#pragma unroll
    for (int r = 0; r < 48; ++r) p[r] = 0.f;
    for (int k = tid; k < 3072; k += 256) {
      float a = xr[k];
      const float* e0 = d0 + (long)k * 16;
      const float* e1 = d1 + (long)k * 16;
      const float* e2 = d2 + (long)k * 16;
#pragma unroll
      for (int r = 0; r < 16; ++r) {
        p[r]      += a * e0[r];
        p[16 + r] += a * e1[r];
        p[32 + r] += a * e2[r];
      }
    }
#pragma unroll
    for (int r = 0; r < 48; ++r)
#pragma unroll
      for (int st = 1; st < 64; st <<= 1) p[r] += __shfl_xor(p[r], st, 64);
    int lane = tid & 63, w = tid >> 6;
    if (lane == 0) {
#pragma unroll
      for (int r = 0; r < 48; ++r) red[w][r] = p[r];
    }
    __syncthreads();
    if (tid < 48) {
      int r = tid;
      tl[(long)m * 48 + r] = red[0][r] + red[1][r] + red[2][r] + red[3][r];
    }
  } else if (b < 7553) {  // wod_prep
    const int m = b - 4480;  // 0..3072
    float (*red)[16] = (float(*)[16])lmem;
    const float* xr = (m < 3072) ? Wo + (long)m * 3072 : bo;
    float p[16];
#pragma unroll
    for (int r = 0; r < 16; ++r) p[r] = 0.f;
    for (int k = tid; k < 3072; k += 256) {
      float a = xr[k];
      const float* d = lp_dn + (long)k * 16;
#pragma unroll
      for (int r = 0; r < 16; ++r) p[r] += a * d[r];
    }
#pragma unroll
    for (int r = 0; r < 16; ++r)
#pragma unroll
      for (int st = 1; st < 64; st <<= 1) p[r] += __shfl_xor(p[r], st, 64);
    int lane = tid & 63, w = tid >> 6;
    if (lane == 0) {
#pragma unroll
      for (int r = 0; r < 16; ++r) red[w][r] = p[r];
    }
    __syncthreads();
    if (tid < 16) {
      int r = tid;
      Wod[(long)m * 16 + r] = red[0][r] + red[1][r] + red[2][r] + red[3][r];
    }
  } else {  // prep section
    const int pb = b - 7553;
    if (pb < 3136) {  // hs -> hsb (ld 3136, cols 3072.. ZERO; t_hs fills later)
      long idx = (long)pb * 256 + tid;
      long m = idx / 392, c = idx % 392;
      U16x4 o0{0, 0, 0, 0}, o1{0, 0, 0, 0};
      if (c < 384) {
        const float* p = hs + m * 3072 + c * 8;
        float4 a = *(const float4*)p;
        float4 bb = *(const float4*)(p + 4);
        o0 = U16x4{f2bf(a.x), f2bf(a.y), f2bf(a.z), f2bf(a.w)};
        o1 = U16x4{f2bf(bb.x), f2bf(bb.y), f2bf(bb.z), f2bf(bb.w)};
      }
      u16* d = hsb + m * 3136 + c * 8;
      *(U16x4*)d = o0;
      *(U16x4*)(d + 4) = o1;
    } else if (pb < 3904) {  // ehs convert
      long i = ((long)(pb - 3136) * 256 + tid) * 8;
      float4 a = *(const float4*)(ehs + i);
      float4 bb = *(const float4*)(ehs + i + 4);
      *(U16x4*)(ehsb + i) = U16x4{f2bf(a.x), f2bf(a.y), f2bf(a.z), f2bf(a.w)};
      *(U16x4*)(ehsb + i + 4) = U16x4{f2bf(bb.x), f2bf(bb.y), f2bf(bb.z), f2bf(bb.w)};
    } else if (pb < 4000) {  // img convert
      long i = ((long)(pb - 3904) * 256 + tid) * 8;
      float4 a = *(const float4*)(img + i);
      float4 bb = *(const float4*)(img + i + 4);
      *(U16x4*)(imgb + i) = U16x4{f2bf(a.x), f2bf(a.y), f2bf(a.z), f2bf(a.w)};
      *(U16x4*)(imgb + i + 4) = U16x4{f2bf(bb.x), f2bf(bb.y), f2bf(bb.z), f2bf(bb.w)};
    } else if (pb < 4072) {  // bias packs
      int i = (pb - 4000) * 256 + tid;
      if (i < 9216)
        bpk[i] = (i < 3072) ? baq[i] : (i < 6144) ? bak[i - 3072] : bav[i - 6144];
      else {
        int j = i - 9216;
        bpk[i] = (j < 3072) ? bq[j] : (j < 6144) ? bk[j - 3072] : bv[j - 6144];
      }
    } else {  // QKV weight K-tails
      int idx = (pb - 4072) * 256 + tid;  // 9216*64
      int n = idx >> 6, i = idx & 63;
      int seg = n / 3072;
      const float* up = (seg == 0) ? u0 : (seg == 1) ? u1 : u2;
      int r = i - seg * 16;
      float v = (r >= 0 && r < 16) ? up[(long)r * 3072 + (n - seg * 3072)] : 0.f;
      WTbM[(long)n * 3136 + 3072 + i] = f2bf(v);
    }
  }
}

// ---------------- t_hs: write LoRA t into hsb K-tail rows 1024+ ----------------
__launch_bounds__(256)
__global__ void t_hs(const float* __restrict__ tl, u16* __restrict__ hsb) {
  int idx = blockIdx.x * 256 + threadIdx.x;  // 1024*48
  int m = idx / 48, r = idx % 48;
  hsb[(long)(1024 + m) * 3136 + 3072 + r] = f2bf(tl[m * 48 + r]);
}

// ---------------- XL Wkip/Wvip transpose -> E1/E2 (ld 3072) ----------------
__launch_bounds__(256)
__global__ void transpose_kv(const float* __restrict__ Wkip, const float* __restrict__ Wvip,
                             u16* __restrict__ E1) {
  __shared__ float t2[4][4][32][33];
  const int b = blockIdx.x;  // 1152
  int mat = b / 576, tile = b % 576;
  const float* src = mat ? Wvip : Wkip;
  u16* dst = E1 + (long)mat * 3072 * 3072;
  const int tid = threadIdx.x;
  int k0 = (tile / 24) * 128, n0 = (tile % 24) * 128;
  int r = tid >> 3, c4 = (tid & 7) * 4;
  float4 v[4][4];
#pragma unroll
  for (int i = 0; i < 4; ++i)
#pragma unroll
    for (int j = 0; j < 4; ++j)
      v[i][j] = *(const float4*)(src + (long)(k0 + i * 32 + r) * 3072 + n0 + j * 32 + c4);
#pragma unroll
  for (int i = 0; i < 4; ++i)
#pragma unroll
    for (int j = 0; j < 4; ++j) {
      t2[i][j][r][c4 + 0] = v[i][j].x; t2[i][j][r][c4 + 1] = v[i][j].y;
      t2[i][j][r][c4 + 2] = v[i][j].z; t2[i][j][r][c4 + 3] = v[i][j].w;
    }
  __syncthreads();
#pragma unroll
  for (int j = 0; j < 4; ++j)
#pragma unroll
    for (int i = 0; i < 4; ++i) {
      U16x4 o{f2bf(t2[i][j][c4 + 0][r]), f2bf(t2[i][j][c4 + 1][r]),
              f2bf(t2[i][j][c4 + 2][r]), f2bf(t2[i][j][c4 + 3][r])};
      *(U16x4*)(dst + (long)(n0 + j * 32 + r) * 3072 + k0 + i * 32 + c4) = o;
    }
}

// ---------------- generic 128-col-tile GEMM -> f32 (IP partials, K-split via z) ----------------
template <int BM, int MI, int NI>
__launch_bounds__(256)
__global__ void gemm_f32(const u16* __restrict__ A, int lda,
                         const u16* __restrict__ B, int ldb,
                         float* __restrict__ C, int ldc,
                         const float* __restrict__ bias, int KC, long cstride) {
  constexpr int WCOLS = 128 / (NI * 16);
  constexpr int ABYTES = BM * 128;
  __shared__ char smem[ABYTES + 128 * 128];
  char* As = smem;
  char* Bs = smem + ABYTES;
  const int tid = threadIdx.x;
  const int w = tid >> 6, lane = tid & 63;
  const int lr = lane & 15, lg = lane >> 4;
  const int wr = w / WCOLS, wc = w % WCOLS;
  const int nbx = gridDim.x;
  const int nwg = nbx * gridDim.y;
  const int flat = blockIdx.y * nbx + blockIdx.x;
  const int swz = (flat & 7) * (nwg >> 3) + (flat >> 3);
  const long m0 = (long)(swz % nbx) * BM;
  const long n0 = (long)(swz / nbx) * 128;
  const int k0 = blockIdx.z * KC;
  C += blockIdx.z * cstride;
  f32x4 acc[MI][NI] = {};
  constexpr int ACH = BM / 32;
  for (int kb = k0; kb < k0 + KC; kb += 64) {
    __syncthreads();
#pragma unroll
    for (int i = 0; i < ACH; ++i) {
      int x = (tid + 256 * i) * 16;
      int row = x >> 7;
      int sx = x ^ ((row & 7) << 4);
      async16((const char*)(A + (m0 + row) * lda + kb) + (sx & 127),
              As + ((w << 10) + (i << 12)));
    }
#pragma unroll
    for (int i = 0; i < 4; ++i) {
      int x = (tid + 256 * i) * 16;
      int row = x >> 7;
      int sx = x ^ ((row & 7) << 4);
      async16((const char*)(B + (n0 + row) * ldb + kb) + (sx & 127),
              Bs + ((w << 10) + (i << 12)));
    }
    __syncthreads();
#pragma unroll
    for (int kc = 0; kc < 2; ++kc) {
      s16x8 af[MI], bfr[NI];
#pragma unroll
      for (int mi = 0; mi < MI; ++mi) {
        int row = wr * (MI * 16) + mi * 16 + lr;
        int b = ((row << 7) + kc * 64 + lg * 16) ^ ((row & 7) << 4);
        af[mi] = *(const s16x8*)(As + b);
      }
#pragma unroll
      for (int ni = 0; ni < NI; ++ni) {
        int row = wc * (NI * 16) + ni * 16 + lr;
        int b = ((row << 7) + kc * 64 + lg * 16) ^ ((row & 7) << 4);
        bfr[ni] = *(const s16x8*)(Bs + b);
      }
#pragma unroll
      for (int mi = 0; mi < MI; ++mi)
#pragma unroll
        for (int ni = 0; ni < NI; ++ni)
          acc[mi][ni] = __builtin_amdgcn_mfma_f32_16x16x32_bf16(af[mi], bfr[ni], acc[mi][ni], 0, 0, 0);
    }
  }
#pragma unroll
  for (int mi = 0; mi < MI; ++mi) {
#pragma unroll
    for (int ni = 0; ni < NI; ++ni) {
      long col = n0 + wc * (NI * 16) + ni * 16 + lr;
      float bv = bias ? bias[col] : 0.f;
#pragma unroll
      for (int j = 0; j < 4; ++j) {
        long row = m0 + wr * (MI * 16) + mi * 16 + lg * 4 + j;
        C[row * ldc + col] = acc[mi][ni][j] + bv;
      }
    }
  }
}

// ---------------- IP: sum 8 K-split partials + RMS(K) / transposed V write ----------------
__launch_bounds__(256)
__global__ void rms_ip(const float* __restrict__ in, u16* __restrict__ Ko,
                       u16* __restrict__ VipT) {
  const int t = blockIdx.x & 63;
  const int vhalf = blockIdx.x >> 6;
  const int col0 = vhalf ? 3072 : 0;
  const int w = threadIdx.x >> 6, lane = threadIdx.x & 63;
  const long ps = 64LL * 6144;
#pragma unroll
  for (int hh = 0; hh < 6; ++hh) {
    int h = w * 6 + hh;
    const float* x = in + (long)t * 6144 + col0 + h * 128 + lane * 2;
    float a = 0.f, b = 0.f;
#pragma unroll
    for (int z = 0; z < 8; ++z) {
      a += x[z * ps];
      b += x[1 + z * ps];
    }
    if (!vhalf) {
      float ss = a * a + b * b;
#pragma unroll
      for (int st = 1; st < 64; st <<= 1) ss += __shfl_xor(ss, st, 64);
      float scale = rsqrtf(ss * (1.f / 128.f) + 1e-5f);
      unsigned pa = f2bf(a * scale), pb = f2bf(b * scale);
      *(unsigned*)(Ko + ((long)h * 64 + t) * 128 + lane * 2) = pa | (pb << 16);
    } else {  // V: write transposed VipT[h][d][t]
      VipT[((long)h * 128 + lane * 2) * 64 + t] = f2bf(a);
      VipT[((long)h * 128 + lane * 2 + 1) * 64 + t] = f2bf(b);
    }
  }
}

// ---------------- fused QKV GEMM: BM=128 x BN=128 (tile = one head), 3 blocks/CU ----------------
__launch_bounds__(256, 3)
__global__ void gemm_qkv(const u16* __restrict__ Aenc, const u16* __restrict__ Amain,
                         const u16* __restrict__ Benc, const u16* __restrict__ Bmain,
                         u16* __restrict__ Qo, u16* __restrict__ Ko, u16* __restrict__ VTo,
                         const float* __restrict__ bpk) {
  __shared__ char smem[32768];
  char* As = smem;
  char* Bs = smem + 16384;
  const int tid = threadIdx.x;
  const int w = tid >> 6, lane = tid & 63;
  const int lr = lane & 15, lg = lane >> 4;
  const int wr = w >> 1, wc = w & 1;
  const int flat = blockIdx.y * 20 + blockIdx.x;  // 1440 blocks
  const int swz = (flat & 7) * 180 + (flat >> 3);
  const int mx = swz % 20;
  const long n0 = (long)(swz / 20) * 128;
  const u16* A;
  const u16* B;
  const float* bias;
  int lda, ldb, K, t0;
  long m0;
  if (mx < 4) {
    A = Aenc; lda = 3072; B = Benc; ldb = 3072; K = 3072; t0 = 0;
    m0 = (long)mx * 128; bias = bpk;
  } else {
    A = Amain; lda = 3136; B = Bmain; ldb = 3136; K = 3136; t0 = 512;
    m0 = (long)(mx - 4) * 128; bias = bpk + 9216;
  }
  f32x4 acc[4][4] = {};
  for (int kb = 0; kb < K; kb += 64) {
    __syncthreads();
#pragma unroll
    for (int i = 0; i < 4; ++i) {
      int x = (tid + 256 * i) * 16;
      int row = x >> 7;
      int sx = (x & 127) ^ ((row & 7) << 4);
      async16((const char*)(A + (m0 + row) * lda + kb) + sx, As + x);
    }
#pragma unroll
    for (int i = 0; i < 4; ++i) {
      int x = (tid + 256 * i) * 16;
      int row = x >> 7;
      int sx = (x & 127) ^ ((row & 7) << 4);
      async16((const char*)(B + (n0 + row) * ldb + kb) + sx, Bs + x);
    }
    __syncthreads();
#pragma unroll
    for (int kc = 0; kc < 2; ++kc) {
      s16x8 af[4], bfr[4];
#pragma unroll
      for (int mi = 0; mi < 4; ++mi) {
        int row = wr * 64 + mi * 16 + lr;
        af[mi] = *(const s16x8*)(As + (row << 7) + ((kc * 64 + lg * 16) ^ ((row & 7) << 4)));
      }
#pragma unroll
      for (int ni = 0; ni < 4; ++ni) {
        int row = wc * 64 + ni * 16 + lr;
        bfr[ni] = *(const s16x8*)(Bs + (row << 7) + ((kc * 64 + lg * 16) ^ ((row & 7) << 4)));
      }
#pragma unroll
      for (int mi = 0; mi < 4; ++mi)
#pragma unroll
        for (int ni = 0; ni < 4; ++ni)
          acc[mi][ni] = __builtin_amdgcn_mfma_f32_16x16x32_bf16(af[mi], bfr[ni], acc[mi][ni], 0, 0, 0);
    }
  }
  const int seg = (int)(n0 / 3072);
  const int head = (int)((n0 % 3072) >> 7);
#pragma unroll
  for (int ni = 0; ni < 4; ++ni) {
    float bv = bias[n0 + wc * 64 + ni * 16 + lr];
#pragma unroll
    for (int mi = 0; mi < 4; ++mi)
#pragma unroll
      for (int j = 0; j < 4; ++j) acc[mi][ni][j] += bv;
  }
  __syncthreads();
  float scl[4][4];
  if (seg < 2) {
    float* red = (float*)smem;
#pragma unroll
    for (int mi = 0; mi < 4; ++mi)
#pragma unroll
      for (int j = 0; j < 4; ++j) {
        float s = 0.f;
#pragma unroll
        for (int ni = 0; ni < 4; ++ni) s += acc[mi][ni][j] * acc[mi][ni][j];
#pragma unroll
        for (int st = 1; st < 16; st <<= 1) s += __shfl_xor(s, st, 16);
        if (lr == 0) red[(wr * 64 + mi * 16 + lg * 4 + j) * 2 + wc] = s;
        scl[mi][j] = s;
      }
    __syncthreads();
#pragma unroll
    for (int mi = 0; mi < 4; ++mi)
#pragma unroll
      for (int j = 0; j < 4; ++j) {
        int row = wr * 64 + mi * 16 + lg * 4 + j;
        float t = red[row * 2] + red[row * 2 + 1];
        scl[mi][j] = rsqrtf(t * (1.f / 128.f) + 1e-5f);
      }
    __syncthreads();
  }
  if (seg < 2) {
#pragma unroll
    for (int mi = 0; mi < 4; ++mi)
#pragma unroll
      for (int ni = 0; ni < 4; ++ni) {
        int d2 = (wc * 64 + ni * 16 + lr) * 2;
#pragma unroll
        for (int j = 0; j < 4; ++j) {
          int tok = wr * 64 + mi * 16 + lg * 4 + j;
          *(u16*)(smem + tok * 256 + (d2 ^ ((tok & 7) << 4))) =
              f2bf(acc[mi][ni][j] * scl[mi][j]);
        }
      }
  } else {
#pragma unroll
    for (int mi = 0; mi < 4; ++mi)
#pragma unroll
      for (int ni = 0; ni < 4; ++ni) {
        int d = wc * 64 + ni * 16 + lr;
        int tok0b = (wr * 64 + mi * 16 + lg * 4) * 2;
        U16x4 o{f2bf(acc[mi][ni][0]), f2bf(acc[mi][ni][1]),
                f2bf(acc[mi][ni][2]), f2bf(acc[mi][ni][3])};
        *(U16x4*)(smem + d * 256 + (tok0b ^ ((d & 7) << 4))) = o;
      }
  }
  __syncthreads();
#pragma unroll
  for (int i = 0; i < 8; ++i) {
    int x = (tid + 256 * i) * 16;
    int row = x >> 8, col = x & 255;
    s16x8 vdat = *(const s16x8*)(smem + row * 256 + (col ^ ((row & 7) << 4)));
    if (seg < 2) {
      u16* g = (seg == 0 ? Qo : Ko) + ((long)head * 2560 + t0 + m0 + row) * 128;
      *(s16x8*)((char*)g + col) = vdat;
    } else {
      u16* g = VTo + ((long)head * 128 + row) * 2560 + t0 + m0;
      *(s16x8*)((char*)g + col) = vdat;
    }
  }
}

// ---------------- attn MEGA: attention + XL Wao/Wo transposes + lp_up tail ----------------
// [0,480): attention (long q-blocks first); [480,1632): XL 128x128 transpose
// tiles (1 per 512-thr block, Wao->WTbE s0, Wo->WTbM s0); [1632,2016): lp_up K-tail.
__launch_bounds__(512, 2)
__global__ void attn_mega(const u16* __restrict__ QB, const u16* __restrict__ KB,
                          const u16* __restrict__ VT, const u16* __restrict__ KipB,
                          const u16* __restrict__ VipT, u16* __restrict__ OutTok,
                          const float* __restrict__ Wao, const float* __restrict__ Wo,
                          u16* __restrict__ WTbE, u16* __restrict__ WTbM,
                          const float* __restrict__ lp_up) {
  __shared__ char smem[81920];
  const int bf = blockIdx.x;
  const int tid = threadIdx.x;
  if (bf >= 480) {
    if (bf < 1632) {  // XL transpose: 128k x 128n per 512-thread block
      int t2i = bf - 480;  // 0..1151
      int mat = t2i / 576, tile = t2i % 576;
      const float* src = mat ? Wo : Wao;
      u16* dst = mat ? WTbM : WTbE;
      const int ldd = mat ? 3136 : 3072;
      float (*t2)[4][32][33] = (float(*)[4][32][33])smem;
      int k0 = (tile / 24) * 128, n0t = (tile % 24) * 128;
      int half = tid >> 8, lt = tid & 255;  // half: i in {2*half, 2*half+1}
      int r = lt >> 3, c4 = (lt & 7) * 4;
      float4 v[2][4];
#pragma unroll
      for (int ii = 0; ii < 2; ++ii)
#pragma unroll
        for (int j = 0; j < 4; ++j)
          v[ii][j] = *(const float4*)(src + (long)(k0 + (half * 2 + ii) * 32 + r) * 3072 +
                                      n0t + j * 32 + c4);
#pragma unroll
      for (int ii = 0; ii < 2; ++ii)
#pragma unroll
        for (int j = 0; j < 4; ++j) {
          int i = half * 2 + ii;
          t2[i][j][r][c4 + 0] = v[ii][j].x; t2[i][j][r][c4 + 1] = v[ii][j].y;
          t2[i][j][r][c4 + 2] = v[ii][j].z; t2[i][j][r][c4 + 3] = v[ii][j].w;
        }
      __syncthreads();
#pragma unroll
      for (int jj = 0; jj < 2; ++jj)
#pragma unroll
        for (int i = 0; i < 4; ++i) {
          int j = half * 2 + jj;
          U16x4 o{f2bf(t2[i][j][c4 + 0][r]), f2bf(t2[i][j][c4 + 1][r]),
                  f2bf(t2[i][j][c4 + 2][r]), f2bf(t2[i][j][c4 + 3][r])};
          *(U16x4*)(dst + (long)(n0t + j * 32 + r) * ldd + k0 + i * 32 + c4) = o;
        }
    } else {  // Wo K-tail = lp_up
      int idx = (bf - 1632) * 512 + tid;  // 3072*64
      int n = idx >> 6, i = idx & 63;
      float v = (i < 16) ? lp_up[(long)i * 3072 + n] : 0.f;
      WTbM[(long)n * 3136 + 3072 + i] = f2bf(v);
    }
    return;
  }
  // ---- attention ----
  const int w = tid >> 6, lane = tid & 63;
  const int lr = lane & 15, lg = lane >> 4;
  int h, qb;
  if (bf < 288) { h = bf / 12; qb = bf % 12; }            // long (40 KV tiles)
  else { int s = bf - 288; h = s / 8; qb = 12 + s % 8; }  // short (16 tiles)
  const int q0 = qb * 128;
  const bool ip = (q0 >= 512);
  const u16* Qrow = QB + (long)(h * 2560 + q0 + w * 16 + lr) * 128;
  s16x8 qf[4];
#pragma unroll
  for (int dc = 0; dc < 4; ++dc) qf[dc] = *(const s16x8*)(Qrow + dc * 32 + lg * 8);
  f32x4 accO[8] = {};
  float l_r[4] = {0.f, 0.f, 0.f, 0.f};
  const int kv0 = (q0 >= 1536) ? 1536 : 0;
  const float sc = 0.08838834764831845f;

  auto stage_main = [&](int kv, int buf) {
#pragma unroll
    for (int i = 0; i < 2; ++i) {
      int x = (tid + 512 * i) * 16;
      int row = x >> 8;
      int sx = x ^ ((row & 7) << 4);
      async16((const char*)(KB + (long)(h * 2560 + kv + row) * 128) + (sx & 255),
              smem + buf * 16384 + ((i << 13) + (w << 10)));
    }
#pragma unroll
    for (int i = 0; i < 2; ++i) {
      int x = (tid + 512 * i) * 16;
      int row = x >> 7;
      int sx = x ^ ((row & 7) << 4);
      async16((const char*)(VT + (long)(h * 128 + row) * 2560 + kv) + (sx & 127),
              smem + 32768 + buf * 16384 + ((i << 13) + (w << 10)));
    }
  };
  auto stage_ip = [&](int buf) {
#pragma unroll
    for (int i = 0; i < 2; ++i) {
      int x = (tid + 512 * i) * 16;
      int row = x >> 8;
      int sx = x ^ ((row & 7) << 4);
      async16((const char*)(KipB + (long)(h * 64 + row) * 128) + (sx & 255),
              smem + buf * 16384 + ((i << 13) + (w << 10)));
    }
#pragma unroll
    for (int i = 0; i < 2; ++i) {
      int x = (tid + 512 * i) * 16;
      int row = x >> 7;
      int sx = x ^ ((row & 7) << 4);
      async16((const char*)(VipT + (long)(h * 128 + row) * 64) + (sx & 127),
              smem + 32768 + buf * 16384 + ((i << 13) + (w << 10)));
    }
  };

  stage_main(kv0, 0);
  __syncthreads();
  int cur = 0;
  for (int kv = kv0; kv < 2560; kv += 64) {
    if (kv + 64 < 2560) stage_main(kv + 64, cur ^ 1);
    else if (ip) stage_ip(cur ^ 1);
    const char* Ks = smem + cur * 16384;
    const char* Vs = smem + 32768 + cur * 16384;
    char* Pw = smem + 65536 + w * 2048;
    f32x4 s[4] = {};
    __builtin_amdgcn_s_setprio(1);
#pragma unroll
    for (int kt = 0; kt < 4; ++kt)
#pragma unroll
      for (int dc = 0; dc < 4; ++dc) {
        int row = kt * 16 + lr;
        int b = ((row << 8) + dc * 64 + lg * 16) ^ ((row & 7) << 4);
        s16x8 kf = *(const s16x8*)(Ks + b);
        s[kt] = __builtin_amdgcn_mfma_f32_16x16x32_bf16(qf[dc], kf, s[kt], 0, 0, 0);
      }
    __builtin_amdgcn_s_setprio(0);
#pragma unroll
    for (int kt = 0; kt < 4; ++kt)
#pragma unroll
      for (int j = 0; j < 4; ++j) {
        float pv = __expf(fmaf(s[kt][j], sc, -12.0f));
        l_r[j] += pv;
        int prow = lg * 4 + j;
        int b = ((prow << 7) + (kt * 16 + lr) * 2) ^ ((prow & 7) << 4);
        *(u16*)(Pw + b) = f2bf(pv);
      }
    asm volatile("s_waitcnt lgkmcnt(0)" ::: "memory");
    __builtin_amdgcn_s_setprio(1);
#pragma unroll
    for (int kc = 0; kc < 2; ++kc) {
      int pb = ((lr << 7) + kc * 64 + lg * 16) ^ ((lr & 7) << 4);
      s16x8 pf = *(const s16x8*)(Pw + pb);
#pragma unroll
      for (int dt = 0; dt < 8; ++dt) {
        int row = dt * 16 + lr;
        int b = ((row << 7) + kc * 64 + lg * 16) ^ ((row & 7) << 4);
        s16x8 vf = *(const s16x8*)(Vs + b);
        accO[dt] = __builtin_amdgcn_mfma_f32_16x16x32_bf16(pf, vf, accO[dt], 0, 0, 0);
      }
    }
    __builtin_amdgcn_s_setprio(0);
    __syncthreads();
    cur ^= 1;
  }
#pragma unroll
  for (int j = 0; j < 4; ++j) {
#pragma unroll
    for (int st = 1; st < 16; st <<= 1) l_r[j] += __shfl_xor(l_r[j], st, 16);
    l_r[j] = 1.f / l_r[j];
  }
#pragma unroll
  for (int dt = 0; dt < 8; ++dt)
#pragma unroll
    for (int j = 0; j < 4; ++j) accO[dt][j] *= l_r[j];
  if (ip) {
    const char* Ks = smem + cur * 16384;
    const char* Vs = smem + 32768 + cur * 16384;
    char* Pw = smem + 65536 + w * 2048;
    f32x4 s2[4] = {};
#pragma unroll
    for (int kt = 0; kt < 4; ++kt)
#pragma unroll
      for (int dc = 0; dc < 4; ++dc) {
        int row = kt * 16 + lr;
        int b = ((row << 8) + dc * 64 + lg * 16) ^ ((row & 7) << 4);
        s16x8 kf = *(const s16x8*)(Ks + b);
        s2[kt] = __builtin_amdgcn_mfma_f32_16x16x32_bf16(qf[dc], kf, s2[kt], 0, 0, 0);
      }
    float p2[4][4];
    float l2[4] = {0.f, 0.f, 0.f, 0.f};
#pragma unroll
    for (int kt = 0; kt < 4; ++kt)
#pragma unroll
      for (int j = 0; j < 4; ++j) {
        float pv = __expf(fmaf(s2[kt][j], sc, -12.0f));
        p2[kt][j] = pv;
        l2[j] += pv;
      }
#pragma unroll
    for (int j = 0; j < 4; ++j) {
#pragma unroll
      for (int st = 1; st < 16; st <<= 1) l2[j] += __shfl_xor(l2[j], st, 16);
      l2[j] = 1.f / l2[j];
    }
#pragma unroll
    for (int kt = 0; kt < 4; ++kt)
#pragma unroll
      for (int j = 0; j < 4; ++j) {
        int prow = lg * 4 + j;
        int b = ((prow << 7) + (kt * 16 + lr) * 2) ^ ((prow & 7) << 4);
        *(u16*)(Pw + b) = f2bf(p2[kt][j] * l2[j]);
      }
    asm volatile("s_waitcnt lgkmcnt(0)" ::: "memory");
#pragma unroll
    for (int kc = 0; kc < 2; ++kc) {
      int pb = ((lr << 7) + kc * 64 + lg * 16) ^ ((lr & 7) << 4);
      s16x8 pf = *(const s16x8*)(Pw + pb);
#pragma unroll
      for (int dt = 0; dt < 8; ++dt) {
        int row = dt * 16 + lr;
        int b = ((row << 7) + kc * 64 + lg * 16) ^ ((row & 7) << 4);
        s16x8 vf = *(const s16x8*)(Vs + b);
        accO[dt] = __builtin_amdgcn_mfma_f32_16x16x32_bf16(pf, vf, accO[dt], 0, 0, 0);
      }
    }
  }
#pragma unroll
  for (int j = 0; j < 4; ++j) {
    long tok = q0 + w * 16 + lg * 4 + j;
#pragma unroll
    for (int dt = 0; dt < 8; ++dt) {
      long col = h * 128 + dt * 16 + lr;
      OutTok[tok * 3136 + col] = f2bf(accO[dt][j]);
    }
  }
}

// ---------------- AttnTok K-tail ----------------
__launch_bounds__(256)
__global__ void t_tail(u16* __restrict__ At, const float* __restrict__ Wod) {
  __shared__ float red[4][16];
  const int tok = blockIdx.x;
  u16* tail = At + (long)(512 + tok) * 3136 + 3072;
  if (tok < 1024) {
    if (threadIdx.x < 64) tail[threadIdx.x] = 0;
    return;
  }
  const u16* xr = At + (long)(512 + tok) * 3136;
  float p[16];
#pragma unroll
  for (int r = 0; r < 16; ++r) p[r] = 0.f;
  for (int n = threadIdx.x; n < 3072; n += 256) {
    float a = bf2f(xr[n]);
    const float* wd = Wod + (long)n * 16;
#pragma unroll
    for (int r = 0; r < 16; ++r) p[r] += a * wd[r];
  }
#pragma unroll
  for (int r = 0; r < 16; ++r)
#pragma unroll
    for (int st = 1; st < 64; st <<= 1) p[r] += __shfl_xor(p[r], st, 64);
  int lane = threadIdx.x & 63, w = threadIdx.x >> 6;
  if (lane == 0) {
#pragma unroll
    for (int r = 0; r < 16; ++r) red[w][r] = p[r];
  }
  __syncthreads();
  if (threadIdx.x < 64) {
    if (threadIdx.x < 16) {
      int r = threadIdx.x;
      float t = red[0][r] + red[1][r] + red[2][r] + red[3][r] + Wod[3072L * 16 + r];
      tail[r] = f2bf(t);
    } else {
      tail[threadIdx.x] = 0;
    }
  }
}

// ---------------- fused output projection: enc(Wao,K=3072) + main(Wo+lp_up,K=3136) ----------------
__launch_bounds__(256)
__global__ void gemm_out(const u16* __restrict__ Atok, const u16* __restrict__ Benc,
                         const u16* __restrict__ Bmain, float* __restrict__ outp,
                         const float* __restrict__ bao, const float* __restrict__ bo) {
  __shared__ char smem[128 * 128 + 128 * 128];
  char* As = smem;
  char* Bs = smem + 128 * 128;
  const int tid = threadIdx.x;
  const int w = tid >> 6, lane = tid & 63;
  const int lr = lane & 15, lg = lane >> 4;
  const int wr = w >> 1, wc = w & 1;
  const int flat = blockIdx.y * 20 + blockIdx.x;
  const int swz = (flat & 7) * 60 + (flat >> 3);
  const int mx = swz % 20;
  const long n0 = (long)(swz / 20) * 128;
  const u16* A;
  const u16* B;
  const float* bias;
  float* C;
  int ldb, K;
  long m0;
  if (mx < 4) {
    A = Atok; B = Benc; ldb = 3072; K = 3072; bias = bao; C = outp;
    m0 = (long)mx * 128;
  } else {
    A = Atok + 512L * 3136; B = Bmain; ldb = 3136; K = 3136; bias = bo;
    C = outp + 512L * 3072; m0 = (long)(mx - 4) * 128;
  }
  f32x4 acc[4][4] = {};
  for (int kb = 0; kb < K; kb += 64) {
    __syncthreads();
#pragma unroll
    for (int i = 0; i < 4; ++i) {
      int x = (tid + 256 * i) * 16;
      int row = x >> 7;
      int sx = x ^ ((row & 7) << 4);
      async16((const char*)(A + (m0 + row) * 3136 + kb) + (sx & 127),
              As + ((w << 10) + (i << 12)));
    }
#pragma unroll
    for (int i = 0; i < 4; ++i) {
      int x = (tid + 256 * i) * 16;
      int row = x >> 7;
      int sx = x ^ ((row & 7) << 4);
      async16((const char*)(B + (n0 + row) * ldb + kb) + (sx & 127),
              Bs + ((w << 10) + (i << 12)));
    }
    __syncthreads();
#pragma unroll
    for (int kc = 0; kc < 2; ++kc) {
      s16x8 af[4], bfr[4];
#pragma unroll
      for (int mi = 0; mi < 4; ++mi) {
        int row = wr * 64 + mi * 16 + lr;
        int b = ((row << 7) + kc * 64 + lg * 16) ^ ((row & 7) << 4);
        af[mi] = *(const s16x8*)(As + b);
      }
#pragma unroll
      for (int ni = 0; ni < 4; ++ni) {
        int row = wc * 64 + ni * 16 + lr;
        int b = ((row << 7) + kc * 64 + lg * 16) ^ ((row & 7) << 4);
        bfr[ni] = *(const s16x8*)(Bs + b);
      }
#pragma unroll
      for (int mi = 0; mi < 4; ++mi)
#pragma unroll
        for (int ni = 0; ni < 4; ++ni)
          acc[mi][ni] = __builtin_amdgcn_mfma_f32_16x16x32_bf16(af[mi], bfr[ni], acc[mi][ni], 0, 0, 0);
    }
  }
#pragma unroll
  for (int mi = 0; mi < 4; ++mi) {
#pragma unroll
    for (int ni = 0; ni < 4; ++ni) {
      long col = n0 + wc * 64 + ni * 16 + lr;
      float bv = bias[col];
#pragma unroll
      for (int j = 0; j < 4; ++j) {
        long row = m0 + wr * 64 + mi * 16 + lg * 4 + j;
        C[row * 3072 + col] = acc[mi][ni][j] + bv;
      }
    }
  }
}

// =====================================================================

extern "C" void kernel_launch(void* const* d_in, const int* in_sizes, int n_in,
                              void* d_out, int out_size, void* d_ws, size_t ws_size,
                              hipStream_t stream) {
  const float* hs    = (const float*)d_in[0];
  const float* ehs   = (const float*)d_in[1];
  const float* img   = (const float*)d_in[2];
  const float* Wq    = (const float*)d_in[3];
  const float* bq    = (const float*)d_in[4];
  const float* Wk    = (const float*)d_in[5];
  const float* bk    = (const float*)d_in[6];
  const float* Wv    = (const float*)d_in[7];
  const float* bv    = (const float*)d_in[8];
  const float* Waq   = (const float*)d_in[9];
  const float* baq   = (const float*)d_in[10];
  const float* Wak   = (const float*)d_in[11];
  const float* bak   = (const float*)d_in[12];
  const float* Wav   = (const float*)d_in[13];
  const float* bav   = (const float*)d_in[14];
  const float* Wo    = (const float*)d_in[15];
  const float* bo    = (const float*)d_in[16];
  const float* Wao   = (const float*)d_in[17];
  const float* bao   = (const float*)d_in[18];
  const float* Wkip  = (const float*)d_in[19];
  const float* Wvip  = (const float*)d_in[20];
  const float* lq_dn = (const float*)d_in[21];
  const float* lq_up = (const float*)d_in[22];
  const float* lk_dn = (const float*)d_in[23];
  const float* lk_up = (const float*)d_in[24];
  const float* lv_dn = (const float*)d_in[25];
  const float* lv_up = (const float*)d_in[26];
  const float* lp_dn = (const float*)d_in[27];
  const float* lp_up = (const float*)d_in[28];
  float* outp = (float*)d_out;

  char* ws = (char*)d_ws;
  size_t off = 0;
  auto take = [&](size_t b) { char* p = ws + off; off += (b + 255) & ~(size_t)255; return p; };
  u16*   WTbE = (u16*)take(3LL * 3072 * 3072 * 2);
  u16*   WTbM = (u16*)take(3LL * 3072 * 3136 * 2);
  u16*   hsb  = (u16*)take(2048LL * 3136 * 2);
  u16*   ehsb = (u16*)take(512LL * 3072 * 2);
  u16*   imgb = (u16*)take(64LL * 3072 * 2);
  u16*   VTf  = (u16*)take(24LL * 128 * 2560 * 2);
  float* IP0  = (float*)take(8LL * 64 * 6144 * 4);
  u16*   KipB = (u16*)take(24LL * 64 * 128 * 2);
  u16*   VipT = (u16*)take(24LL * 128 * 64 * 2);
  float* bpk  = (float*)take(2 * 9216 * 4);
  float* tl   = (float*)take(1024LL * 48 * 4);
  float* Wod  = (float*)take(3073LL * 16 * 4);
  u16* QBf = (u16*)d_out;                 // alias: d_out dead until gemm_out
  u16* KBf = (u16*)d_out + 24LL * 2560 * 128;
  u16* AttnTok = hsb;                     // alias: hsb dead after gemm_qkv
  u16* E1 = WTbE + 3072LL * 3072;

  // D1: mega prep (6 XL transposes + lora_dn3 + wod + converts/bias/tails)
  mega_prep<<<13929, 256, 0, stream>>>(Waq, Wak, Wav, Wq, Wk, Wv, WTbE, WTbM,
                                       Wo, bo, lp_dn, Wod,
                                       lq_dn, lk_dn, lv_dn, tl,
                                       hs, hsb, ehs, ehsb, img, imgb,
                                       baq, bak, bav, bq, bk, bv, bpk,
                                       lq_up, lk_up, lv_up);
  // D2: LoRA t into hsb K-tail
  t_hs<<<192, 256, 0, stream>>>(tl, hsb);

  // D3: fused enc+main QKV GEMM (1440 blocks, 3/CU)
  gemm_qkv<<<dim3(20, 72), 256, 0, stream>>>(ehsb, hsb, WTbE, WTbM, QBf, KBf, VTf, bpk);

  // D4: XL Wkip/Wvip transpose into E1/E2 (slots free after D3)
  transpose_kv<<<1152, 256, 0, stream>>>(Wkip, Wvip, E1);

  // D5: IP projections (K-split x8, MFMA)
  gemm_f32<64, 4, 2><<<dim3(1, 48, 8), 256, 0, stream>>>(imgb, 3072, E1, 3072, IP0, 6144,
                                                          nullptr, 384, 64LL * 6144);
  // D6: fused sum/RMS(K) + transposed Vip write
  rms_ip<<<128, 256, 0, stream>>>(IP0, KipB, VipT);

  // D7: attention MEGA (attn + XL Wao/Wo transposes + lp_up tail, co-scheduled)
  attn_mega<<<2016, 512, 0, stream>>>(QBf, KBf, VTf, KipB, VipT, AttnTok,
                                      Wao, Wo, WTbE, WTbM, lp_up);

  // D8: LoRA-p t into AttnTok K-tail
  t_tail<<<2048, 256, 0, stream>>>(AttnTok, Wod);

  // D9: fused output projection (lp folded in K)
  gemm_out<<<dim3(20, 24), 256, 0, stream>>>(AttnTok, WTbE, WTbM, outp, bao, bo);
}

// Round 16
// 557.284 us; speedup vs baseline: 1.0257x; 1.0257x over previous
//
#include <hip/hip_runtime.h>

typedef unsigned short u16;
typedef short s16x8 __attribute__((ext_vector_type(8)));
typedef float f32x4 __attribute__((ext_vector_type(4)));
typedef const __attribute__((address_space(1))) unsigned int* as1_u32p;
typedef __attribute__((address_space(3))) unsigned int* as3_u32p;

static_assert(sizeof(s16x8) == 16, "");

struct alignas(8) U16x4 { u16 x, y, z, w; };

__device__ __forceinline__ u16 f2bf(float f) {
  union { float f; unsigned u; } c; c.f = f;
  return (u16)((c.u + 0x7fffu + ((c.u >> 16) & 1u)) >> 16);
}
__device__ __forceinline__ float bf2f(u16 h) {
  union { unsigned u; float f; } c; c.u = ((unsigned)h) << 16;
  return c.f;
}
__device__ __forceinline__ void async16(const void* g, void* l) {
  __builtin_amdgcn_global_load_lds((as1_u32p)g, (as3_u32p)l, 16, 0, 0);
}

// ---------------- MEGA prep ----------------
// [0,13824): FAT transpose {Waq,Wak,Wav}->WTbE(3072), {Wq,Wk,Wv}->WTbM(3136),
//   128k x 32n per block, n-tile ROTATED per k-band (channel de-resonance):
//   concurrent k-bands differ by 1.5MB = 0 mod C*G, so axis-aligned tiling
//   concentrates on few HBM channels; j' = (j + 13*i + 29*mat) % 96 spreads it.
// [13824,14848): lora_dn3 -> tl
// [14848,17921): Wod[k][16] = Wo[k,:]@lp_dn (row 3072 = bo@lp_dn)
// [17921,24297): hs convert (tail zeroed), ehs, img, bias packs, WTbM QKV K-tails
__launch_bounds__(256)
__global__ void mega_prep(const float* __restrict__ Waq, const float* __restrict__ Wak,
                          const float* __restrict__ Wav, const float* __restrict__ Wq,
                          const float* __restrict__ Wk, const float* __restrict__ Wv,
                          u16* __restrict__ WTbE, u16* __restrict__ WTbM,
                          const float* __restrict__ Wo, const float* __restrict__ bo,
                          const float* __restrict__ lp_dn, float* __restrict__ Wod,
                          const float* __restrict__ d0, const float* __restrict__ d1,
                          const float* __restrict__ d2, float* __restrict__ tl,
                          const float* __restrict__ hs, u16* __restrict__ hsb,
                          const float* __restrict__ ehs, u16* __restrict__ ehsb,
                          const float* __restrict__ img, u16* __restrict__ imgb,
                          const float* __restrict__ baq, const float* __restrict__ bak,
                          const float* __restrict__ bav, const float* __restrict__ bq,
                          const float* __restrict__ bk, const float* __restrict__ bv,
                          float* __restrict__ bpk,
                          const float* __restrict__ u0, const float* __restrict__ u1,
                          const float* __restrict__ u2) {
  __shared__ char lmem[16896];
  const int b = blockIdx.x;
  const int tid = threadIdx.x;
  if (b < 13824) {  // fat transpose: 128k x 32n, rotated n-tile
    int mat = b / 2304, tile = b % 2304;
    const float* src = (mat == 0) ? Waq : (mat == 1) ? Wak : (mat == 2) ? Wav
                       : (mat == 3) ? Wq : (mat == 4) ? Wk : Wv;
    u16* dst = (mat < 3) ? WTbE + (long)mat * 3072 * 3072
                         : WTbM + (long)(mat - 3) * 3072 * 3136;
    const int ldd = (mat < 3) ? 3072 : 3136;
    float (*tile2)[32][33] = (float(*)[32][33])lmem;
    int ti = tile / 96, tj = tile % 96;
    int tjr = (tj + ti * 13 + mat * 29) % 96;  // channel de-resonance rotation
    int k0 = ti * 128, n0 = tjr * 32;
    int r = tid >> 3, c4 = (tid & 7) * 4;
    float4 v[4];
#pragma unroll
    for (int t = 0; t < 4; ++t)
      v[t] = *(const float4*)(src + (long)(k0 + 32 * t + r) * 3072 + n0 + c4);
#pragma unroll
    for (int t = 0; t < 4; ++t) {
      tile2[t][r][c4 + 0] = v[t].x; tile2[t][r][c4 + 1] = v[t].y;
      tile2[t][r][c4 + 2] = v[t].z; tile2[t][r][c4 + 3] = v[t].w;
    }
    __syncthreads();
#pragma unroll
    for (int t = 0; t < 4; ++t) {
      U16x4 o{f2bf(tile2[t][c4 + 0][r]), f2bf(tile2[t][c4 + 1][r]),
              f2bf(tile2[t][c4 + 2][r]), f2bf(tile2[t][c4 + 3][r])};
      *(U16x4*)(dst + (long)(n0 + r) * ldd + k0 + 32 * t + c4) = o;
    }
  } else if (b < 14848) {  // lora_dn3
    const int m = b - 13824;
    float (*red)[48] = (float(*)[48])lmem;
    const float* xr = hs + (long)(1024 + m) * 3072;
    float p[48];
#pragma unroll
    for (int r = 0; r < 48; ++r) p[r] = 0.f;
    for (int k = tid; k < 3072; k += 256) {
      float a = xr[k];
      const float* e0 = d0 + (long)k * 16;
      const float* e1 = d1 + (long)k * 16;
      const float* e2 = d2 + (long)k * 16;
#pragma unroll
      for (int r = 0; r < 16; ++r) {
        p[r]      += a * e0[r];
        p[16 + r] += a * e1[r];
        p[32 + r] += a * e2[r];
      }
    }
#pragma unroll
    for (int r = 0; r < 48; ++r)
#pragma unroll
      for (int st = 1; st < 64; st <<= 1) p[r] += __shfl_xor(p[r], st, 64);
    int lane = tid & 63, w = tid >> 6;
    if (lane == 0) {
#pragma unroll
      for (int r = 0; r < 48; ++r) red[w][r] = p[r];
    }
    __syncthreads();
    if (tid < 48) {
      int r = tid;
      tl[(long)m * 48 + r] = red[0][r] + red[1][r] + red[2][r] + red[3][r];
    }
  } else if (b < 17921) {  // wod_prep
    const int m = b - 14848;  // 0..3072
    float (*red)[16] = (float(*)[16])lmem;
    const float* xr = (m < 3072) ? Wo + (long)m * 3072 : bo;
    float p[16];
#pragma unroll
    for (int r = 0; r < 16; ++r) p[r] = 0.f;
    for (int k = tid; k < 3072; k += 256) {
      float a = xr[k];
      const float* d = lp_dn + (long)k * 16;
#pragma unroll
      for (int r = 0; r < 16; ++r) p[r] += a * d[r];
    }
#pragma unroll
    for (int r = 0; r < 16; ++r)
#pragma unroll
      for (int st = 1; st < 64; st <<= 1) p[r] += __shfl_xor(p[r], st, 64);
    int lane = tid & 63, w = tid >> 6;
    if (lane == 0) {
#pragma unroll
      for (int r = 0; r < 16; ++r) red[w][r] = p[r];
    }
    __syncthreads();
    if (tid < 16) {
      int r = tid;
      Wod[(long)m * 16 + r] = red[0][r] + red[1][r] + red[2][r] + red[3][r];
    }
  } else {  // prep section
    const int pb = b - 17921;
    if (pb < 3136) {  // hs -> hsb (ld 3136, cols 3072.. ZERO; t_hs fills later)
      long idx = (long)pb * 256 + tid;
      long m = idx / 392, c = idx % 392;
      U16x4 o0{0, 0, 0, 0}, o1{0, 0, 0, 0};
      if (c < 384) {
        const float* p = hs + m * 3072 + c * 8;
        float4 a = *(const float4*)p;
        float4 bb = *(const float4*)(p + 4);
        o0 = U16x4{f2bf(a.x), f2bf(a.y), f2bf(a.z), f2bf(a.w)};
        o1 = U16x4{f2bf(bb.x), f2bf(bb.y), f2bf(bb.z), f2bf(bb.w)};
      }
      u16* d = hsb + m * 3136 + c * 8;
      *(U16x4*)d = o0;
      *(U16x4*)(d + 4) = o1;
    } else if (pb < 3904) {  // ehs convert
      long i = ((long)(pb - 3136) * 256 + tid) * 8;
      float4 a = *(const float4*)(ehs + i);
      float4 bb = *(const float4*)(ehs + i + 4);
      *(U16x4*)(ehsb + i) = U16x4{f2bf(a.x), f2bf(a.y), f2bf(a.z), f2bf(a.w)};
      *(U16x4*)(ehsb + i + 4) = U16x4{f2bf(bb.x), f2bf(bb.y), f2bf(bb.z), f2bf(bb.w)};
    } else if (pb < 4000) {  // img convert
      long i = ((long)(pb - 3904) * 256 + tid) * 8;
      float4 a = *(const float4*)(img + i);
      float4 bb = *(const float4*)(img + i + 4);
      *(U16x4*)(imgb + i) = U16x4{f2bf(a.x), f2bf(a.y), f2bf(a.z), f2bf(a.w)};
      *(U16x4*)(imgb + i + 4) = U16x4{f2bf(bb.x), f2bf(bb.y), f2bf(bb.z), f2bf(bb.w)};
    } else if (pb < 4072) {  // bias packs
      int i = (pb - 4000) * 256 + tid;
      if (i < 9216)
        bpk[i] = (i < 3072) ? baq[i] : (i < 6144) ? bak[i - 3072] : bav[i - 6144];
      else {
        int j = i - 9216;
        bpk[i] = (j < 3072) ? bq[j] : (j < 6144) ? bk[j - 3072] : bv[j - 6144];
      }
    } else {  // QKV weight K-tails
      int idx = (pb - 4072) * 256 + tid;  // 9216*64
      int n = idx >> 6, i = idx & 63;
      int seg = n / 3072;
      const float* up = (seg == 0) ? u0 : (seg == 1) ? u1 : u2;
      int r = i - seg * 16;
      float v = (r >= 0 && r < 16) ? up[(long)r * 3072 + (n - seg * 3072)] : 0.f;
      WTbM[(long)n * 3136 + 3072 + i] = f2bf(v);
    }
  }
}

// ---------------- t_hs: write LoRA t into hsb K-tail rows 1024+ ----------------
__launch_bounds__(256)
__global__ void t_hs(const float* __restrict__ tl, u16* __restrict__ hsb) {
  int idx = blockIdx.x * 256 + threadIdx.x;  // 1024*48
  int m = idx / 48, r = idx % 48;
  hsb[(long)(1024 + m) * 3136 + 3072 + r] = f2bf(tl[m * 48 + r]);
}

// ---------------- FAT Wkip/Wvip transpose -> E1/E2 (ld 3072), rotated ----------------
__launch_bounds__(256)
__global__ void transpose_kv(const float* __restrict__ Wkip, const float* __restrict__ Wvip,
                             u16* __restrict__ E1) {
  __shared__ float tile2[4][32][33];
  const int b = blockIdx.x;  // 4608
  int mat = b / 2304, tile = b % 2304;
  const float* src = mat ? Wvip : Wkip;
  u16* dst = E1 + (long)mat * 3072 * 3072;
  const int tid = threadIdx.x;
  int ti = tile / 96, tj = tile % 96;
  int tjr = (tj + ti * 13 + mat * 29) % 96;  // channel de-resonance rotation
  int k0 = ti * 128, n0 = tjr * 32;
  int r = tid >> 3, c4 = (tid & 7) * 4;
  float4 v[4];
#pragma unroll
  for (int t = 0; t < 4; ++t)
    v[t] = *(const float4*)(src + (long)(k0 + 32 * t + r) * 3072 + n0 + c4);
#pragma unroll
  for (int t = 0; t < 4; ++t) {
    tile2[t][r][c4 + 0] = v[t].x; tile2[t][r][c4 + 1] = v[t].y;
    tile2[t][r][c4 + 2] = v[t].z; tile2[t][r][c4 + 3] = v[t].w;
  }
  __syncthreads();
#pragma unroll
  for (int t = 0; t < 4; ++t) {
    U16x4 o{f2bf(tile2[t][c4 + 0][r]), f2bf(tile2[t][c4 + 1][r]),
            f2bf(tile2[t][c4 + 2][r]), f2bf(tile2[t][c4 + 3][r])};
    *(U16x4*)(dst + (long)(n0 + r) * 3072 + k0 + 32 * t + c4) = o;
  }
}

// ---------------- generic 128-col-tile GEMM -> f32 (IP partials, K-split via z) ----------------
template <int BM, int MI, int NI>
__launch_bounds__(256)
__global__ void gemm_f32(const u16* __restrict__ A, int lda,
                         const u16* __restrict__ B, int ldb,
                         float* __restrict__ C, int ldc,
                         const float* __restrict__ bias, int KC, long cstride) {
  constexpr int WCOLS = 128 / (NI * 16);
  constexpr int ABYTES = BM * 128;
  __shared__ char smem[ABYTES + 128 * 128];
  char* As = smem;
  char* Bs = smem + ABYTES;
  const int tid = threadIdx.x;
  const int w = tid >> 6, lane = tid & 63;
  const int lr = lane & 15, lg = lane >> 4;
  const int wr = w / WCOLS, wc = w % WCOLS;
  const int nbx = gridDim.x;
  const int nwg = nbx * gridDim.y;
  const int flat = blockIdx.y * nbx + blockIdx.x;
  const int swz = (flat & 7) * (nwg >> 3) + (flat >> 3);
  const long m0 = (long)(swz % nbx) * BM;
  const long n0 = (long)(swz / nbx) * 128;
  const int k0 = blockIdx.z * KC;
  C += blockIdx.z * cstride;
  f32x4 acc[MI][NI] = {};
  constexpr int ACH = BM / 32;
  for (int kb = k0; kb < k0 + KC; kb += 64) {
    __syncthreads();
#pragma unroll
    for (int i = 0; i < ACH; ++i) {
      int x = (tid + 256 * i) * 16;
      int row = x >> 7;
      int sx = x ^ ((row & 7) << 4);
      async16((const char*)(A + (m0 + row) * lda + kb) + (sx & 127),
              As + ((w << 10) + (i << 12)));
    }
#pragma unroll
    for (int i = 0; i < 4; ++i) {
      int x = (tid + 256 * i) * 16;
      int row = x >> 7;
      int sx = x ^ ((row & 7) << 4);
      async16((const char*)(B + (n0 + row) * ldb + kb) + (sx & 127),
              Bs + ((w << 10) + (i << 12)));
    }
    __syncthreads();
#pragma unroll
    for (int kc = 0; kc < 2; ++kc) {
      s16x8 af[MI], bfr[NI];
#pragma unroll
      for (int mi = 0; mi < MI; ++mi) {
        int row = wr * (MI * 16) + mi * 16 + lr;
        int b = ((row << 7) + kc * 64 + lg * 16) ^ ((row & 7) << 4);
        af[mi] = *(const s16x8*)(As + b);
      }
#pragma unroll
      for (int ni = 0; ni < NI; ++ni) {
        int row = wc * (NI * 16) + ni * 16 + lr;
        int b = ((row << 7) + kc * 64 + lg * 16) ^ ((row & 7) << 4);
        bfr[ni] = *(const s16x8*)(Bs + b);
      }
#pragma unroll
      for (int mi = 0; mi < MI; ++mi)
#pragma unroll
        for (int ni = 0; ni < NI; ++ni)
          acc[mi][ni] = __builtin_amdgcn_mfma_f32_16x16x32_bf16(af[mi], bfr[ni], acc[mi][ni], 0, 0, 0);
    }
  }
#pragma unroll
  for (int mi = 0; mi < MI; ++mi) {
#pragma unroll
    for (int ni = 0; ni < NI; ++ni) {
      long col = n0 + wc * (NI * 16) + ni * 16 + lr;
      float bv = bias ? bias[col] : 0.f;
#pragma unroll
      for (int j = 0; j < 4; ++j) {
        long row = m0 + wr * (MI * 16) + mi * 16 + lg * 4 + j;
        C[row * ldc + col] = acc[mi][ni][j] + bv;
      }
    }
  }
}

// ---------------- IP: sum 4 K-split partials + RMS(K) / transposed V write ----------------
__launch_bounds__(256)
__global__ void rms_ip(const float* __restrict__ in, u16* __restrict__ Ko,
                       u16* __restrict__ VipT) {
  const int t = blockIdx.x & 63;
  const int vhalf = blockIdx.x >> 6;
  const int col0 = vhalf ? 3072 : 0;
  const int w = threadIdx.x >> 6, lane = threadIdx.x & 63;
  const long ps = 64LL * 6144;
#pragma unroll
  for (int hh = 0; hh < 6; ++hh) {
    int h = w * 6 + hh;
    const float* x = in + (long)t * 6144 + col0 + h * 128 + lane * 2;
    float a = x[0] + x[ps] + x[2 * ps] + x[3 * ps];
    float b = x[1] + x[1 + ps] + x[1 + 2 * ps] + x[1 + 3 * ps];
    if (!vhalf) {
      float ss = a * a + b * b;
#pragma unroll
      for (int st = 1; st < 64; st <<= 1) ss += __shfl_xor(ss, st, 64);
      float scale = rsqrtf(ss * (1.f / 128.f) + 1e-5f);
      unsigned pa = f2bf(a * scale), pb = f2bf(b * scale);
      *(unsigned*)(Ko + ((long)h * 64 + t) * 128 + lane * 2) = pa | (pb << 16);
    } else {  // V: write transposed VipT[h][d][t]
      VipT[((long)h * 128 + lane * 2) * 64 + t] = f2bf(a);
      VipT[((long)h * 128 + lane * 2 + 1) * 64 + t] = f2bf(b);
    }
  }
}

// ---------------- fused QKV GEMM: BM=128 x BN=128 (tile = one head), 3 blocks/CU ----------------
__launch_bounds__(256, 3)
__global__ void gemm_qkv(const u16* __restrict__ Aenc, const u16* __restrict__ Amain,
                         const u16* __restrict__ Benc, const u16* __restrict__ Bmain,
                         u16* __restrict__ Qo, u16* __restrict__ Ko, u16* __restrict__ VTo,
                         const float* __restrict__ bpk) {
  __shared__ char smem[32768];
  char* As = smem;
  char* Bs = smem + 16384;
  const int tid = threadIdx.x;
  const int w = tid >> 6, lane = tid & 63;
  const int lr = lane & 15, lg = lane >> 4;
  const int wr = w >> 1, wc = w & 1;
  const int flat = blockIdx.y * 20 + blockIdx.x;  // 1440 blocks
  const int swz = (flat & 7) * 180 + (flat >> 3);
  const int mx = swz % 20;
  const long n0 = (long)(swz / 20) * 128;
  const u16* A;
  const u16* B;
  const float* bias;
  int lda, ldb, K, t0;
  long m0;
  if (mx < 4) {
    A = Aenc; lda = 3072; B = Benc; ldb = 3072; K = 3072; t0 = 0;
    m0 = (long)mx * 128; bias = bpk;
  } else {
    A = Amain; lda = 3136; B = Bmain; ldb = 3136; K = 3136; t0 = 512;
    m0 = (long)(mx - 4) * 128; bias = bpk + 9216;
  }
  f32x4 acc[4][4] = {};
  for (int kb = 0; kb < K; kb += 64) {
    __syncthreads();
#pragma unroll
    for (int i = 0; i < 4; ++i) {
      int x = (tid + 256 * i) * 16;
      int row = x >> 7;
      int sx = (x & 127) ^ ((row & 7) << 4);
      async16((const char*)(A + (m0 + row) * lda + kb) + sx, As + x);
    }
#pragma unroll
    for (int i = 0; i < 4; ++i) {
      int x = (tid + 256 * i) * 16;
      int row = x >> 7;
      int sx = (x & 127) ^ ((row & 7) << 4);
      async16((const char*)(B + (n0 + row) * ldb + kb) + sx, Bs + x);
    }
    __syncthreads();
#pragma unroll
    for (int kc = 0; kc < 2; ++kc) {
      s16x8 af[4], bfr[4];
#pragma unroll
      for (int mi = 0; mi < 4; ++mi) {
        int row = wr * 64 + mi * 16 + lr;
        af[mi] = *(const s16x8*)(As + (row << 7) + ((kc * 64 + lg * 16) ^ ((row & 7) << 4)));
      }
#pragma unroll
      for (int ni = 0; ni < 4; ++ni) {
        int row = wc * 64 + ni * 16 + lr;
        bfr[ni] = *(const s16x8*)(Bs + (row << 7) + ((kc * 64 + lg * 16) ^ ((row & 7) << 4)));
      }
#pragma unroll
      for (int mi = 0; mi < 4; ++mi)
#pragma unroll
        for (int ni = 0; ni < 4; ++ni)
          acc[mi][ni] = __builtin_amdgcn_mfma_f32_16x16x32_bf16(af[mi], bfr[ni], acc[mi][ni], 0, 0, 0);
    }
  }
  const int seg = (int)(n0 / 3072);
  const int head = (int)((n0 % 3072) >> 7);
#pragma unroll
  for (int ni = 0; ni < 4; ++ni) {
    float bv = bias[n0 + wc * 64 + ni * 16 + lr];
#pragma unroll
    for (int mi = 0; mi < 4; ++mi)
#pragma unroll
      for (int j = 0; j < 4; ++j) acc[mi][ni][j] += bv;
  }
  __syncthreads();
  float scl[4][4];
  if (seg < 2) {
    float* red = (float*)smem;
#pragma unroll
    for (int mi = 0; mi < 4; ++mi)
#pragma unroll
      for (int j = 0; j < 4; ++j) {
        float s = 0.f;
#pragma unroll
        for (int ni = 0; ni < 4; ++ni) s += acc[mi][ni][j] * acc[mi][ni][j];
#pragma unroll
        for (int st = 1; st < 16; st <<= 1) s += __shfl_xor(s, st, 16);
        if (lr == 0) red[(wr * 64 + mi * 16 + lg * 4 + j) * 2 + wc] = s;
        scl[mi][j] = s;
      }
    __syncthreads();
#pragma unroll
    for (int mi = 0; mi < 4; ++mi)
#pragma unroll
      for (int j = 0; j < 4; ++j) {
        int row = wr * 64 + mi * 16 + lg * 4 + j;
        float t = red[row * 2] + red[row * 2 + 1];
        scl[mi][j] = rsqrtf(t * (1.f / 128.f) + 1e-5f);
      }
    __syncthreads();
  }
  if (seg < 2) {
#pragma unroll
    for (int mi = 0; mi < 4; ++mi)
#pragma unroll
      for (int ni = 0; ni < 4; ++ni) {
        int d2 = (wc * 64 + ni * 16 + lr) * 2;
#pragma unroll
        for (int j = 0; j < 4; ++j) {
          int tok = wr * 64 + mi * 16 + lg * 4 + j;
          *(u16*)(smem + tok * 256 + (d2 ^ ((tok & 7) << 4))) =
              f2bf(acc[mi][ni][j] * scl[mi][j]);
        }
      }
  } else {
#pragma unroll
    for (int mi = 0; mi < 4; ++mi)
#pragma unroll
      for (int ni = 0; ni < 4; ++ni) {
        int d = wc * 64 + ni * 16 + lr;
        int tok0b = (wr * 64 + mi * 16 + lg * 4) * 2;
        U16x4 o{f2bf(acc[mi][ni][0]), f2bf(acc[mi][ni][1]),
                f2bf(acc[mi][ni][2]), f2bf(acc[mi][ni][3])};
        *(U16x4*)(smem + d * 256 + (tok0b ^ ((d & 7) << 4))) = o;
      }
  }
  __syncthreads();
#pragma unroll
  for (int i = 0; i < 8; ++i) {
    int x = (tid + 256 * i) * 16;
    int row = x >> 8, col = x & 255;
    s16x8 vdat = *(const s16x8*)(smem + row * 256 + (col ^ ((row & 7) << 4)));
    if (seg < 2) {
      u16* g = (seg == 0 ? Qo : Ko) + ((long)head * 2560 + t0 + m0 + row) * 128;
      *(s16x8*)((char*)g + col) = vdat;
    } else {
      u16* g = VTo + ((long)head * 128 + row) * 2560 + t0 + m0;
      *(s16x8*)((char*)g + col) = vdat;
    }
  }
}

// ---------------- attn MEGA: attention + FAT rotated Wao/Wo transposes + lp_up tail ----------------
// [0,480): attention (long q-blocks first); [480,2784): 2 fat 128x32 rotated
// transpose tiles per 512-thr block; [2784,3168): lp_up K-tail.
__launch_bounds__(512, 2)
__global__ void attn_mega(const u16* __restrict__ QB, const u16* __restrict__ KB,
                          const u16* __restrict__ VT, const u16* __restrict__ KipB,
                          const u16* __restrict__ VipT, u16* __restrict__ OutTok,
                          const float* __restrict__ Wao, const float* __restrict__ Wo,
                          u16* __restrict__ WTbE, u16* __restrict__ WTbM,
                          const float* __restrict__ lp_up) {
  __shared__ char smem[81920];
  const int bf = blockIdx.x;
  const int tid = threadIdx.x;
  if (bf >= 480) {
    if (bf < 2784) {  // fat rotated transpose: 2 x (128k x 32n) tiles per block
      int t2 = (bf - 480) * 2 + (tid >> 8);  // 0..4607
      int mat = t2 / 2304, tile = t2 % 2304;
      const float* src = mat ? Wo : Wao;
      u16* dst = mat ? WTbM : WTbE;
      const int ldd = mat ? 3136 : 3072;
      float (*tl4)[4][32][33] = (float(*)[4][32][33])smem;
      int half = tid >> 8, lt = tid & 255;
      int ti = tile / 96, tj = tile % 96;
      int tjr = (tj + ti * 13 + mat * 29) % 96;  // channel de-resonance rotation
      int k0 = ti * 128, n0t = tjr * 32;
      int r = lt >> 3, c4 = (lt & 7) * 4;
      float4 v[4];
#pragma unroll
      for (int t = 0; t < 4; ++t)
        v[t] = *(const float4*)(src + (long)(k0 + 32 * t + r) * 3072 + n0t + c4);
#pragma unroll
      for (int t = 0; t < 4; ++t) {
        tl4[half][t][r][c4 + 0] = v[t].x; tl4[half][t][r][c4 + 1] = v[t].y;
        tl4[half][t][r][c4 + 2] = v[t].z; tl4[half][t][r][c4 + 3] = v[t].w;
      }
      __syncthreads();
#pragma unroll
      for (int t = 0; t < 4; ++t) {
        U16x4 o{f2bf(tl4[half][t][c4 + 0][r]), f2bf(tl4[half][t][c4 + 1][r]),
                f2bf(tl4[half][t][c4 + 2][r]), f2bf(tl4[half][t][c4 + 3][r])};
        *(U16x4*)(dst + (long)(n0t + r) * ldd + k0 + 32 * t + c4) = o;
      }
    } else {  // Wo K-tail = lp_up
      int idx = (bf - 2784) * 512 + tid;  // 3072*64
      int n = idx >> 6, i = idx & 63;
      float v = (i < 16) ? lp_up[(long)i * 3072 + n] : 0.f;
      WTbM[(long)n * 3136 + 3072 + i] = f2bf(v);
    }
    return;
  }
  // ---- attention ----
  const int w = tid >> 6, lane = tid & 63;
  const int lr = lane & 15, lg = lane >> 4;
  int h, qb;
  if (bf < 288) { h = bf / 12; qb = bf % 12; }            // long (40 KV tiles)
  else { int s = bf - 288; h = s / 8; qb = 12 + s % 8; }  // short (16 tiles)
  const int q0 = qb * 128;
  const bool ip = (q0 >= 512);
  const u16* Qrow = QB + (long)(h * 2560 + q0 + w * 16 + lr) * 128;
  s16x8 qf[4];
#pragma unroll
  for (int dc = 0; dc < 4; ++dc) qf[dc] = *(const s16x8*)(Qrow + dc * 32 + lg * 8);
  f32x4 accO[8] = {};
  float l_r[4] = {0.f, 0.f, 0.f, 0.f};
  const int kv0 = (q0 >= 1536) ? 1536 : 0;
  const float sc = 0.08838834764831845f;

  auto stage_main = [&](int kv, int buf) {
#pragma unroll
    for (int i = 0; i < 2; ++i) {
      int x = (tid + 512 * i) * 16;
      int row = x >> 8;
      int sx = x ^ ((row & 7) << 4);
      async16((const char*)(KB + (long)(h * 2560 + kv + row) * 128) + (sx & 255),
              smem + buf * 16384 + ((i << 13) + (w << 10)));
    }
#pragma unroll
    for (int i = 0; i < 2; ++i) {
      int x = (tid + 512 * i) * 16;
      int row = x >> 7;
      int sx = x ^ ((row & 7) << 4);
      async16((const char*)(VT + (long)(h * 128 + row) * 2560 + kv) + (sx & 127),
              smem + 32768 + buf * 16384 + ((i << 13) + (w << 10)));
    }
  };
  auto stage_ip = [&](int buf) {
#pragma unroll
    for (int i = 0; i < 2; ++i) {
      int x = (tid + 512 * i) * 16;
      int row = x >> 8;
      int sx = x ^ ((row & 7) << 4);
      async16((const char*)(KipB + (long)(h * 64 + row) * 128) + (sx & 255),
              smem + buf * 16384 + ((i << 13) + (w << 10)));
    }
#pragma unroll
    for (int i = 0; i < 2; ++i) {
      int x = (tid + 512 * i) * 16;
      int row = x >> 7;
      int sx = x ^ ((row & 7) << 4);
      async16((const char*)(VipT + (long)(h * 128 + row) * 64) + (sx & 127),
              smem + 32768 + buf * 16384 + ((i << 13) + (w << 10)));
    }
  };

  stage_main(kv0, 0);
  __syncthreads();
  int cur = 0;
  for (int kv = kv0; kv < 2560; kv += 64) {
    if (kv + 64 < 2560) stage_main(kv + 64, cur ^ 1);
    else if (ip) stage_ip(cur ^ 1);
    const char* Ks = smem + cur * 16384;
    const char* Vs = smem + 32768 + cur * 16384;
    char* Pw = smem + 65536 + w * 2048;
    f32x4 s[4] = {};
    __builtin_amdgcn_s_setprio(1);
#pragma unroll
    for (int kt = 0; kt < 4; ++kt)
#pragma unroll
      for (int dc = 0; dc < 4; ++dc) {
        int row = kt * 16 + lr;
        int b = ((row << 8) + dc * 64 + lg * 16) ^ ((row & 7) << 4);
        s16x8 kf = *(const s16x8*)(Ks + b);
        s[kt] = __builtin_amdgcn_mfma_f32_16x16x32_bf16(qf[dc], kf, s[kt], 0, 0, 0);
      }
    __builtin_amdgcn_s_setprio(0);
#pragma unroll
    for (int kt = 0; kt < 4; ++kt)
#pragma unroll
      for (int j = 0; j < 4; ++j) {
        float pv = __expf(fmaf(s[kt][j], sc, -12.0f));
        l_r[j] += pv;
        int prow = lg * 4 + j;
        int b = ((prow << 7) + (kt * 16 + lr) * 2) ^ ((prow & 7) << 4);
        *(u16*)(Pw + b) = f2bf(pv);
      }
    asm volatile("s_waitcnt lgkmcnt(0)" ::: "memory");
    __builtin_amdgcn_s_setprio(1);
#pragma unroll
    for (int kc = 0; kc < 2; ++kc) {
      int pb = ((lr << 7) + kc * 64 + lg * 16) ^ ((lr & 7) << 4);
      s16x8 pf = *(const s16x8*)(Pw + pb);
#pragma unroll
      for (int dt = 0; dt < 8; ++dt) {
        int row = dt * 16 + lr;
        int b = ((row << 7) + kc * 64 + lg * 16) ^ ((row & 7) << 4);
        s16x8 vf = *(const s16x8*)(Vs + b);
        accO[dt] = __builtin_amdgcn_mfma_f32_16x16x32_bf16(pf, vf, accO[dt], 0, 0, 0);
      }
    }
    __builtin_amdgcn_s_setprio(0);
    __syncthreads();
    cur ^= 1;
  }
#pragma unroll
  for (int j = 0; j < 4; ++j) {
#pragma unroll
    for (int st = 1; st < 16; st <<= 1) l_r[j] += __shfl_xor(l_r[j], st, 16);
    l_r[j] = 1.f / l_r[j];
  }
#pragma unroll
  for (int dt = 0; dt < 8; ++dt)
#pragma unroll
    for (int j = 0; j < 4; ++j) accO[dt][j] *= l_r[j];
  if (ip) {
    const char* Ks = smem + cur * 16384;
    const char* Vs = smem + 32768 + cur * 16384;
    char* Pw = smem + 65536 + w * 2048;
    f32x4 s2[4] = {};
#pragma unroll
    for (int kt = 0; kt < 4; ++kt)
#pragma unroll
      for (int dc = 0; dc < 4; ++dc) {
        int row = kt * 16 + lr;
        int b = ((row << 8) + dc * 64 + lg * 16) ^ ((row & 7) << 4);
        s16x8 kf = *(const s16x8*)(Ks + b);
        s2[kt] = __builtin_amdgcn_mfma_f32_16x16x32_bf16(qf[dc], kf, s2[kt], 0, 0, 0);
      }
    float p2[4][4];
    float l2[4] = {0.f, 0.f, 0.f, 0.f};
#pragma unroll
    for (int kt = 0; kt < 4; ++kt)
#pragma unroll
      for (int j = 0; j < 4; ++j) {
        float pv = __expf(fmaf(s2[kt][j], sc, -12.0f));
        p2[kt][j] = pv;
        l2[j] += pv;
      }
#pragma unroll
    for (int j = 0; j < 4; ++j) {
#pragma unroll
      for (int st = 1; st < 16; st <<= 1) l2[j] += __shfl_xor(l2[j], st, 16);
      l2[j] = 1.f / l2[j];
    }
#pragma unroll
    for (int kt = 0; kt < 4; ++kt)
#pragma unroll
      for (int j = 0; j < 4; ++j) {
        int prow = lg * 4 + j;
        int b = ((prow << 7) + (kt * 16 + lr) * 2) ^ ((prow & 7) << 4);
        *(u16*)(Pw + b) = f2bf(p2[kt][j] * l2[j]);
      }
    asm volatile("s_waitcnt lgkmcnt(0)" ::: "memory");
#pragma unroll
    for (int kc = 0; kc < 2; ++kc) {
      int pb = ((lr << 7) + kc * 64 + lg * 16) ^ ((lr & 7) << 4);
      s16x8 pf = *(const s16x8*)(Pw + pb);
#pragma unroll
      for (int dt = 0; dt < 8; ++dt) {
        int row = dt * 16 + lr;
        int b = ((row << 7) + kc * 64 + lg * 16) ^ ((row & 7) << 4);
        s16x8 vf = *(const s16x8*)(Vs + b);
        accO[dt] = __builtin_amdgcn_mfma_f32_16x16x32_bf16(pf, vf, accO[dt], 0, 0, 0);
      }
    }
  }
#pragma unroll
  for (int j = 0; j < 4; ++j) {
    long tok = q0 + w * 16 + lg * 4 + j;
#pragma unroll
    for (int dt = 0; dt < 8; ++dt) {
      long col = h * 128 + dt * 16 + lr;
      OutTok[tok * 3136 + col] = f2bf(accO[dt][j]);
    }
  }
}

// ---------------- AttnTok K-tail ----------------
__launch_bounds__(256)
__global__ void t_tail(u16* __restrict__ At, const float* __restrict__ Wod) {
  __shared__ float red[4][16];
  const int tok = blockIdx.x;
  u16* tail = At + (long)(512 + tok) * 3136 + 3072;
  if (tok < 1024) {
    if (threadIdx.x < 64) tail[threadIdx.x] = 0;
    return;
  }
  const u16* xr = At + (long)(512 + tok) * 3136;
  float p[16];
#pragma unroll
  for (int r = 0; r < 16; ++r) p[r] = 0.f;
  for (int n = threadIdx.x; n < 3072; n += 256) {
    float a = bf2f(xr[n]);
    const float* wd = Wod + (long)n * 16;
#pragma unroll
    for (int r = 0; r < 16; ++r) p[r] += a * wd[r];
  }
#pragma unroll
  for (int r = 0; r < 16; ++r)
#pragma unroll
    for (int st = 1; st < 64; st <<= 1) p[r] += __shfl_xor(p[r], st, 64);
  int lane = threadIdx.x & 63, w = threadIdx.x >> 6;
  if (lane == 0) {
#pragma unroll
    for (int r = 0; r < 16; ++r) red[w][r] = p[r];
  }
  __syncthreads();
  if (threadIdx.x < 64) {
    if (threadIdx.x < 16) {
      int r = threadIdx.x;
      float t = red[0][r] + red[1][r] + red[2][r] + red[3][r] + Wod[3072L * 16 + r];
      tail[r] = f2bf(t);
    } else {
      tail[threadIdx.x] = 0;
    }
  }
}

// ---------------- fused output projection: enc(Wao,K=3072) + main(Wo+lp_up,K=3136) ----------------
__launch_bounds__(256)
__global__ void gemm_out(const u16* __restrict__ Atok, const u16* __restrict__ Benc,
                         const u16* __restrict__ Bmain, float* __restrict__ outp,
                         const float* __restrict__ bao, const float* __restrict__ bo) {
  __shared__ char smem[128 * 128 + 128 * 128];
  char* As = smem;
  char* Bs = smem + 128 * 128;
  const int tid = threadIdx.x;
  const int w = tid >> 6, lane = tid & 63;
  const int lr = lane & 15, lg = lane >> 4;
  const int wr = w >> 1, wc = w & 1;
  const int flat = blockIdx.y * 20 + blockIdx.x;
  const int swz = (flat & 7) * 60 + (flat >> 3);
  const int mx = swz % 20;
  const long n0 = (long)(swz / 20) * 128;
  const u16* A;
  const u16* B;
  const float* bias;
  float* C;
  int ldb, K;
  long m0;
  if (mx < 4) {
    A = Atok; B = Benc; ldb = 3072; K = 3072; bias = bao; C = outp;
    m0 = (long)mx * 128;
  } else {
    A = Atok + 512L * 3136; B = Bmain; ldb = 3136; K = 3136; bias = bo;
    C = outp + 512L * 3072; m0 = (long)(mx - 4) * 128;
  }
  f32x4 acc[4][4] = {};
  for (int kb = 0; kb < K; kb += 64) {
    __syncthreads();
#pragma unroll
    for (int i = 0; i < 4; ++i) {
      int x = (tid + 256 * i) * 16;
      int row = x >> 7;
      int sx = x ^ ((row & 7) << 4);
      async16((const char*)(A + (m0 + row) * 3136 + kb) + (sx & 127),
              As + ((w << 10) + (i << 12)));
    }
#pragma unroll
    for (int i = 0; i < 4; ++i) {
      int x = (tid + 256 * i) * 16;
      int row = x >> 7;
      int sx = x ^ ((row & 7) << 4);
      async16((const char*)(B + (n0 + row) * ldb + kb) + (sx & 127),
              Bs + ((w << 10) + (i << 12)));
    }
    __syncthreads();
#pragma unroll
    for (int kc = 0; kc < 2; ++kc) {
      s16x8 af[4], bfr[4];
#pragma unroll
      for (int mi = 0; mi < 4; ++mi) {
        int row = wr * 64 + mi * 16 + lr;
        int b = ((row << 7) + kc * 64 + lg * 16) ^ ((row & 7) << 4);
        af[mi] = *(const s16x8*)(As + b);
      }
#pragma unroll
      for (int ni = 0; ni < 4; ++ni) {
        int row = wc * 64 + ni * 16 + lr;
        int b = ((row << 7) + kc * 64 + lg * 16) ^ ((row & 7) << 4);
        bfr[ni] = *(const s16x8*)(Bs + b);
      }
#pragma unroll
      for (int mi = 0; mi < 4; ++mi)
#pragma unroll
        for (int ni = 0; ni < 4; ++ni)
          acc[mi][ni] = __builtin_amdgcn_mfma_f32_16x16x32_bf16(af[mi], bfr[ni], acc[mi][ni], 0, 0, 0);
    }
  }
#pragma unroll
  for (int mi = 0; mi < 4; ++mi) {
#pragma unroll
    for (int ni = 0; ni < 4; ++ni) {
      long col = n0 + wc * 64 + ni * 16 + lr;
      float bv = bias[col];
#pragma unroll
      for (int j = 0; j < 4; ++j) {
        long row = m0 + wr * 64 + mi * 16 + lg * 4 + j;
        C[row * 3072 + col] = acc[mi][ni][j] + bv;
      }
    }
  }
}

// =====================================================================

extern "C" void kernel_launch(void* const* d_in, const int* in_sizes, int n_in,
                              void* d_out, int out_size, void* d_ws, size_t ws_size,
                              hipStream_t stream) {
  const float* hs    = (const float*)d_in[0];
  const float* ehs   = (const float*)d_in[1];
  const float* img   = (const float*)d_in[2];
  const float* Wq    = (const float*)d_in[3];
  const float* bq    = (const float*)d_in[4];
  const float* Wk    = (const float*)d_in[5];
  const float* bk    = (const float*)d_in[6];
  const float* Wv    = (const float*)d_in[7];
  const float* bv    = (const float*)d_in[8];
  const float* Waq   = (const float*)d_in[9];
  const float* baq   = (const float*)d_in[10];
  const float* Wak   = (const float*)d_in[11];
  const float* bak   = (const float*)d_in[12];
  const float* Wav   = (const float*)d_in[13];
  const float* bav   = (const float*)d_in[14];
  const float* Wo    = (const float*)d_in[15];
  const float* bo    = (const float*)d_in[16];
  const float* Wao   = (const float*)d_in[17];
  const float* bao   = (const float*)d_in[18];
  const float* Wkip  = (const float*)d_in[19];
  const float* Wvip  = (const float*)d_in[20];
  const float* lq_dn = (const float*)d_in[21];
  const float* lq_up = (const float*)d_in[22];
  const float* lk_dn = (const float*)d_in[23];
  const float* lk_up = (const float*)d_in[24];
  const float* lv_dn = (const float*)d_in[25];
  const float* lv_up = (const float*)d_in[26];
  const float* lp_dn = (const float*)d_in[27];
  const float* lp_up = (const float*)d_in[28];
  float* outp = (float*)d_out;

  char* ws = (char*)d_ws;
  size_t off = 0;
  auto take = [&](size_t b) { char* p = ws + off; off += (b + 255) & ~(size_t)255; return p; };
  u16*   WTbE = (u16*)take(3LL * 3072 * 3072 * 2);
  u16*   WTbM = (u16*)take(3LL * 3072 * 3136 * 2);
  u16*   hsb  = (u16*)take(2048LL * 3136 * 2);
  u16*   ehsb = (u16*)take(512LL * 3072 * 2);
  u16*   imgb = (u16*)take(64LL * 3072 * 2);
  u16*   VTf  = (u16*)take(24LL * 128 * 2560 * 2);
  float* IP0  = (float*)take(4LL * 64 * 6144 * 4);
  u16*   KipB = (u16*)take(24LL * 64 * 128 * 2);
  u16*   VipT = (u16*)take(24LL * 128 * 64 * 2);
  float* bpk  = (float*)take(2 * 9216 * 4);
  float* tl   = (float*)take(1024LL * 48 * 4);
  float* Wod  = (float*)take(3073LL * 16 * 4);
  u16* QBf = (u16*)d_out;                 // alias: d_out dead until gemm_out
  u16* KBf = (u16*)d_out + 24LL * 2560 * 128;
  u16* AttnTok = hsb;                     // alias: hsb dead after gemm_qkv
  u16* E1 = WTbE + 3072LL * 3072;

  // D1: mega prep (6 fat rotated transposes + lora_dn3 + wod + converts/bias/tails)
  mega_prep<<<24297, 256, 0, stream>>>(Waq, Wak, Wav, Wq, Wk, Wv, WTbE, WTbM,
                                       Wo, bo, lp_dn, Wod,
                                       lq_dn, lk_dn, lv_dn, tl,
                                       hs, hsb, ehs, ehsb, img, imgb,
                                       baq, bak, bav, bq, bk, bv, bpk,
                                       lq_up, lk_up, lv_up);
  // D2: LoRA t into hsb K-tail
  t_hs<<<192, 256, 0, stream>>>(tl, hsb);

  // D3: fused enc+main QKV GEMM (1440 blocks, 3/CU)
  gemm_qkv<<<dim3(20, 72), 256, 0, stream>>>(ehsb, hsb, WTbE, WTbM, QBf, KBf, VTf, bpk);

  // D4: FAT rotated Wkip/Wvip transpose into E1/E2 (slots free after D3)
  transpose_kv<<<4608, 256, 0, stream>>>(Wkip, Wvip, E1);

  // D5: IP projections (K-split x4, MFMA)
  gemm_f32<64, 4, 2><<<dim3(1, 48, 4), 256, 0, stream>>>(imgb, 3072, E1, 3072, IP0, 6144,
                                                          nullptr, 768, 64LL * 6144);
  // D6: fused sum/RMS(K) + transposed Vip write
  rms_ip<<<128, 256, 0, stream>>>(IP0, KipB, VipT);

  // D7: attention MEGA (attn + fat rotated Wao/Wo transposes + lp_up tail)
  attn_mega<<<3168, 512, 0, stream>>>(QBf, KBf, VTf, KipB, VipT, AttnTok,
                                      Wao, Wo, WTbE, WTbM, lp_up);

  // D8: LoRA-p t into AttnTok K-tail
  t_tail<<<2048, 256, 0, stream>>>(AttnTok, Wod);

  // D9: fused output projection (lp folded in K)
  gemm_out<<<dim3(20, 24), 256, 0, stream>>>(AttnTok, WTbE, WTbM, outp, bao, bo);
}